// Round 5
// baseline (84.005 us; speedup 1.0000x reference)
//
#include <hip/hip_runtime.h>

// ConvNearestNeighbor forward, MI355X (gfx950).
// x: (B=16, C=32, H=32, W=32) f32; neighbors: (NUM=32, C=32, 9) f32
// out[((b*NUM + n)*C + c)*H*W + h*W + w]
//   = max_k | x[b,c,h-row_k,w-col_k] (zero-pad) - neighbors[n,c,k] |,
//   k = 3*(row+1)+(col+1), row,col in {-1,0,1}
//
// Round 5:
//  - PLAIN float4 stores (round 3/4 used nontemporal; fill kernel proves the
//    cached streaming-store path sustains 5.9 TB/s, our NT path ~1.8 TB/s).
//  - NPB 8->4: grid (512,8)=4096 blocks = 2 resident batches/CU, so stage
//    latency of one batch overlaps compute/stores of the other.
//  - launch_bounds(256,4): regalloc headroom (no spill risk); actual VGPR
//    use ~60 keeps 8 blocks/CU residency anyway.
//  - keep: stride-37 tile (<=2-way banks), nlds[n][12] vectorized reads.

#define BB 16
#define CC 32
#define HH 32
#define WW 32
#define NUMN 32
#define NPB 4    // codebook entries per block

typedef float f32x4 __attribute__((ext_vector_type(4)));

__global__ __launch_bounds__(256, 4) void conv_nn_kernel(
    const float* __restrict__ x,
    const float* __restrict__ neighbors,
    float* __restrict__ out)
{
    __shared__ float tile[HH + 2][37];     // stride 37: <=2-way banks
    __shared__ float nlds[NPB][12];        // 48B rows, 16B aligned

    const int bc = blockIdx.x;        // 0 .. B*C-1
    const int b  = bc >> 5;           // / C
    const int c  = bc & 31;           // % C
    const int n0 = blockIdx.y * NPB;  // first codebook entry for this block
    const int t  = threadIdx.x;       // 0..255

    // ---- stage x plane with zero halo (L2-hot: x is only 2 MiB) ----
    const float* xplane = x + (b * CC + c) * (HH * WW);
    for (int idx = t; idx < 34 * 34; idx += 256) {
        int row = idx / 34;           // 0..33
        int col = idx - row * 34;     // 0..33
        int h = row - 1, w = col - 1;
        float v = 0.0f;
        if ((unsigned)h < (unsigned)HH && (unsigned)w < (unsigned)WW)
            v = xplane[h * WW + w];
        tile[row][col] = v;
    }
    // ---- stage neighbors[n0:n0+NPB, c, :] into [n][12] layout ----
    if (t < NPB * 9) {
        int n = t / 9;
        int k = t - n * 9;
        nlds[n][k] = neighbors[((n0 + n) * CC + c) * 9 + k];
    }
    __syncthreads();

    // thread -> (h, w0..w0+3); plane-linear offset = h*W + w0 = 4*t
    const int h  = t >> 3;
    const int w0 = (t & 7) * 4;

    // 3 rows x 6 cols register window of the padded tile
    float xr[3][6];
    #pragma unroll
    for (int r = 0; r < 3; ++r)
        #pragma unroll
        for (int j = 0; j < 6; ++j)
            xr[r][j] = tile[h + r][w0 + j];

    float* oplane = out + (size_t)((b * NUMN + n0) * CC + c) * (HH * WW) + t * 4;
    const int nstride = CC * HH * WW;   // plane stride between consecutive n

    #pragma unroll
    for (int ni = 0; ni < NPB; ++ni) {
        // 9 neighbor taps: vectorized LDS reads (b128 + b128 + b32)
        f32x4 nlo = *reinterpret_cast<const f32x4*>(&nlds[ni][0]);
        f32x4 nhi = *reinterpret_cast<const f32x4*>(&nlds[ni][4]);
        float nb[9] = { nlo.x, nlo.y, nlo.z, nlo.w,
                        nhi.x, nhi.y, nhi.z, nhi.w, nlds[ni][8] };

        // k=0 (rr=0,cc2=0) seeds the max: sample xr[2][j+2]
        float acc0 = fabsf(xr[2][2] - nb[0]);
        float acc1 = fabsf(xr[2][3] - nb[0]);
        float acc2 = fabsf(xr[2][4] - nb[0]);
        float acc3 = fabsf(xr[2][5] - nb[0]);
        #pragma unroll
        for (int kk = 1; kk < 9; ++kk) {
            const int rr  = kk / 3;       // row+1
            const int cc2 = kk - rr * 3;  // col+1
            const float nv = nb[kk];
            acc0 = fmaxf(acc0, fabsf(xr[2 - rr][0 + 2 - cc2] - nv));
            acc1 = fmaxf(acc1, fabsf(xr[2 - rr][1 + 2 - cc2] - nv));
            acc2 = fmaxf(acc2, fabsf(xr[2 - rr][2 + 2 - cc2] - nv));
            acc3 = fmaxf(acc3, fabsf(xr[2 - rr][3 + 2 - cc2] - nv));
        }
        f32x4 v = { acc0, acc1, acc2, acc3 };
        *reinterpret_cast<f32x4*>(oplane + (size_t)ni * nstride) = v;
    }
}

extern "C" void kernel_launch(void* const* d_in, const int* in_sizes, int n_in,
                              void* d_out, int out_size, void* d_ws, size_t ws_size,
                              hipStream_t stream) {
    const float* x         = (const float*)d_in[0];
    const float* neighbors = (const float*)d_in[1];
    float* out             = (float*)d_out;

    dim3 grid(BB * CC, NUMN / NPB);   // (512, 8) = 4096 blocks
    dim3 block(256);
    conv_nn_kernel<<<grid, block, 0, stream>>>(x, neighbors, out);
}

// Round 6
// 83.713 us; speedup vs baseline: 1.0035x; 1.0035x over previous
//
#include <hip/hip_runtime.h>

// ConvNearestNeighbor forward, MI355X (gfx950).
// x: (B=16, C=32, H=32, W=32) f32; neighbors: (NUM=32, C=32, 9) f32
// out[((b*NUM + n)*C + c)*H*W + h*W + w]
//   = max_k | x[b,c,h-row_k,w-col_k] (zero-pad) - neighbors[n,c,k] |,
//   k = 3*(row+1)+(col+1), row,col in {-1,0,1}
//
// Round 6: ZERO-LDS variant. Rounds 3-5 proved store flavor (NT vs plain),
// grid size (2048 vs 4096), and LDS bank behavior are all non-factors.
// Remaining structural suspect: the stage->__syncthreads->LDS-reread pipeline.
//  - each thread reads its 3x6 halo window directly from global (x is 2 MiB,
//    fully L2/L3 resident; one float4 + 2 scalars per row, predicated zeros
//    at the borders)
//  - neighbors indices are block-uniform -> compiler scalarizes to s_load
//    broadcasts (36 floats in SGPRs), no LDS, no barrier at all
//  - plain float4 stores, grid (512, 8) = 4096 blocks

#define BB 16
#define CC 32
#define HH 32
#define WW 32
#define NUMN 32
#define NPB 4    // codebook entries per block

typedef float f32x4 __attribute__((ext_vector_type(4)));

__global__ __launch_bounds__(256) void conv_nn_kernel(
    const float* __restrict__ x,
    const float* __restrict__ neighbors,
    float* __restrict__ out)
{
    const int bc = blockIdx.x;        // 0 .. B*C-1
    const int b  = bc >> 5;           // / C
    const int c  = bc & 31;           // % C
    const int n0 = blockIdx.y * NPB;  // first codebook entry for this block
    const int t  = threadIdx.x;       // 0..255

    // thread -> (h, w0..w0+3); plane-linear offset = h*W + w0 = 4*t
    const int h  = t >> 3;
    const int w0 = (t & 7) * 4;       // 16B-aligned column of the float4

    const float* __restrict__ xplane = x + (b * CC + c) * (HH * WW);

    // 3x6 zero-padded window: xr[r][j] = x[b,c, h-1+r, w0-1+j] (0 outside)
    float xr[3][6];
    #pragma unroll
    for (int r = 0; r < 3; ++r) {
        const int row = h - 1 + r;
        const bool rv = (unsigned)row < (unsigned)HH;
        const float* rp = xplane + row * WW;
        f32x4 mid = {0.0f, 0.0f, 0.0f, 0.0f};
        if (rv) mid = *reinterpret_cast<const f32x4*>(rp + w0);     // aligned
        const float left  = (rv && w0 > 0)      ? rp[w0 - 1] : 0.0f;
        const float right = (rv && w0 + 4 < WW) ? rp[w0 + 4] : 0.0f;
        xr[r][0] = left;  xr[r][1] = mid.x; xr[r][2] = mid.y;
        xr[r][3] = mid.z; xr[r][4] = mid.w; xr[r][5] = right;
    }

    // neighbors for this block: indices are wave-uniform -> s_load broadcasts
    float nb[NPB][9];
    #pragma unroll
    for (int ni = 0; ni < NPB; ++ni)
        #pragma unroll
        for (int k = 0; k < 9; ++k)
            nb[ni][k] = neighbors[((n0 + ni) * CC + c) * 9 + k];

    float* oplane = out + (size_t)((b * NUMN + n0) * CC + c) * (HH * WW) + t * 4;
    const int nstride = CC * HH * WW;   // plane stride between consecutive n

    #pragma unroll
    for (int ni = 0; ni < NPB; ++ni) {
        // k=0 (rr=0,cc2=0) seeds the max: sample xr[2][j+2]
        float acc0 = fabsf(xr[2][2] - nb[ni][0]);
        float acc1 = fabsf(xr[2][3] - nb[ni][0]);
        float acc2 = fabsf(xr[2][4] - nb[ni][0]);
        float acc3 = fabsf(xr[2][5] - nb[ni][0]);
        #pragma unroll
        for (int kk = 1; kk < 9; ++kk) {
            const int rr  = kk / 3;       // row+1
            const int cc2 = kk - rr * 3;  // col+1
            const float nv = nb[ni][kk];
            acc0 = fmaxf(acc0, fabsf(xr[2 - rr][0 + 2 - cc2] - nv));
            acc1 = fmaxf(acc1, fabsf(xr[2 - rr][1 + 2 - cc2] - nv));
            acc2 = fmaxf(acc2, fabsf(xr[2 - rr][2 + 2 - cc2] - nv));
            acc3 = fmaxf(acc3, fabsf(xr[2 - rr][3 + 2 - cc2] - nv));
        }
        f32x4 v = { acc0, acc1, acc2, acc3 };
        *reinterpret_cast<f32x4*>(oplane + (size_t)ni * nstride) = v;
    }
}

extern "C" void kernel_launch(void* const* d_in, const int* in_sizes, int n_in,
                              void* d_out, int out_size, void* d_ws, size_t ws_size,
                              hipStream_t stream) {
    const float* x         = (const float*)d_in[0];
    const float* neighbors = (const float*)d_in[1];
    float* out             = (float*)d_out;

    dim3 grid(BB * CC, NUMN / NPB);   // (512, 8) = 4096 blocks
    dim3 block(256);
    conv_nn_kernel<<<grid, block, 0, stream>>>(x, neighbors, out);
}